// Round 1
// baseline (2466.801 us; speedup 1.0000x reference)
//
#include <hip/hip_runtime.h>
#include <hip/hip_bf16.h>
#include <cstdint>

// Problem constants (fixed by reference: B=16, L=1024, EMBED=1024, 8 heads x 128)
#define EMBED 1024
#define NHEAD 8
#define HID   128
#define MB    16
#define LEN   1024
#define MROWS (MB*LEN)   // 16384 rows for the (b,l)-flattened GEMMs
#define BHT   (NHEAD*MB) // 128 batched heads, bh = h*16 + b

// ---------------------------------------------------------------------------
// Kernel A: Y = X @ W^T + bias, output scattered to head-major (bh, l, H).
// X: (MROWS, EMBED) row-major. W: (EMBED_out=1024, EMBED) row-major (W^T GEMM).
// 64x64 tile, 256 threads, 4x4 microtile, K-tile 16. Classic f32 LDS GEMM.
// ---------------------------------------------------------------------------
__global__ __launch_bounds__(256)
void k_linear_head(const float* __restrict__ X, const float* __restrict__ W,
                   const float* __restrict__ bias, float* __restrict__ Y)
{
    const int M0 = blockIdx.y * 64;
    const int N0 = blockIdx.x * 64;
    __shared__ float As[16][68];  // [k][m], stride 68 floats = 272 B (16B-aligned rows)
    __shared__ float Bs[16][68];  // [k][n]
    const int tid = threadIdx.x;
    const int tx = tid & 15, ty = tid >> 4;
    const int lm = tid >> 2;          // 0..63 row loaded by this thread
    const int lk = (tid & 3) * 4;     // 0,4,8,12 k-offset (float4)
    float c[4][4] = {};

    for (int k0 = 0; k0 < EMBED; k0 += 16) {
        float4 av = *(const float4*)(X + (size_t)(M0 + lm) * EMBED + k0 + lk);
        float4 bv = *(const float4*)(W + (size_t)(N0 + lm) * EMBED + k0 + lk);
        As[lk+0][lm] = av.x; As[lk+1][lm] = av.y; As[lk+2][lm] = av.z; As[lk+3][lm] = av.w;
        Bs[lk+0][lm] = bv.x; Bs[lk+1][lm] = bv.y; Bs[lk+2][lm] = bv.z; Bs[lk+3][lm] = bv.w;
        __syncthreads();
        #pragma unroll
        for (int kk = 0; kk < 16; ++kk) {
            float4 a = *(const float4*)&As[kk][ty*4];
            float4 b = *(const float4*)&Bs[kk][tx*4];
            float ar[4] = {a.x,a.y,a.z,a.w};
            float br[4] = {b.x,b.y,b.z,b.w};
            #pragma unroll
            for (int i = 0; i < 4; ++i)
                #pragma unroll
                for (int j = 0; j < 4; ++j)
                    c[i][j] += ar[i] * br[j];
        }
        __syncthreads();
    }
    #pragma unroll
    for (int i = 0; i < 4; ++i) {
        const int m = M0 + ty*4 + i;
        const int b = m >> 10, l = m & 1023;
        #pragma unroll
        for (int j = 0; j < 4; ++j) {
            const int n = N0 + tx*4 + j;
            const int h = n >> 7, hh = n & 127;
            Y[(((size_t)(h*MB + b))*LEN + l)*HID + hh] = c[i][j] + bias[n];
        }
    }
}

// ---------------------------------------------------------------------------
// Kernel B: sk[row] = dot(kx[row,:], w[0:128]); sq[row] = dot(qx[row,:], w[128:256])
// One wave (64 lanes) per row, 2 elements/lane, shuffle reduce.
// ---------------------------------------------------------------------------
__global__ __launch_bounds__(256)
void k_rowdot(const float* __restrict__ kx, const float* __restrict__ qx,
              const float* __restrict__ w, float* __restrict__ sk, float* __restrict__ sq)
{
    const int gw = (blockIdx.x * 256 + threadIdx.x) >> 6;   // global wave id
    const int lane = threadIdx.x & 63;
    const float* src; const float* wp; float* dst; int row;
    if (gw < BHT*LEN) { src = kx; wp = w;       dst = sk; row = gw; }
    else              { src = qx; wp = w + HID; dst = sq; row = gw - BHT*LEN; }
    const float* r = src + (size_t)row * HID;
    float v = r[lane]*wp[lane] + r[lane+64]*wp[lane+64];
    #pragma unroll
    for (int off = 32; off; off >>= 1) v += __shfl_down(v, off);
    if (lane == 0) dst[row] = v;
}

// ---------------------------------------------------------------------------
// Kernel C: score[bh,q,k] = softmax_k( tanh(sq[bh,q] + sk[bh,k]) )
// tanh output in [-1,1] -> exp in [0.37, 2.72]: no max-subtraction needed.
// One 256-thread block per (bh, q) row of 1024.
// ---------------------------------------------------------------------------
__global__ __launch_bounds__(256)
void k_softmax(const float* __restrict__ sk, const float* __restrict__ sq,
               float* __restrict__ score)
{
    const int bh = blockIdx.y;
    const int qr = blockIdx.x;
    const float sqv = sq[bh*LEN + qr];
    const float* skr = sk + (size_t)bh*LEN;
    const int t = threadIdx.x;
    float e[4];
    float sum = 0.f;
    #pragma unroll
    for (int i = 0; i < 4; ++i) {
        const float x  = sqv + skr[t + 256*i];
        const float t2 = __expf(2.f * x);                       // e^{2x}
        const float th = 1.f - 2.f * __builtin_amdgcn_rcpf(t2 + 1.f); // tanh(x)
        e[i] = __expf(th);
        sum += e[i];
    }
    __shared__ float red[4];
    #pragma unroll
    for (int off = 32; off; off >>= 1) sum += __shfl_down(sum, off);
    if ((t & 63) == 0) red[t >> 6] = sum;
    __syncthreads();
    const float inv = __builtin_amdgcn_rcpf(red[0] + red[1] + red[2] + red[3]);
    float* out = score + ((size_t)bh*LEN + qr)*LEN;
    #pragma unroll
    for (int i = 0; i < 4; ++i) out[t + 256*i] = e[i] * inv;
}

// ---------------------------------------------------------------------------
// Kernel D: attn[bh] = score[bh] (1024x1024) @ kx[bh] (1024x128), batched over 128.
// 64(q) x 128(full H) tile per block, 256 threads, 4x8 microtile, K-tile 16.
// ---------------------------------------------------------------------------
__global__ __launch_bounds__(256)
void k_attnmm(const float* __restrict__ score, const float* __restrict__ kx,
              float* __restrict__ attn)
{
    const int bh = blockIdx.y;
    const int q0 = blockIdx.x * 64;
    __shared__ float Ss[16][68];   // [k][m]
    __shared__ float Ks[16][132];  // [k][n], stride 132 floats = 528 B (16B-aligned)
    const int tid = threadIdx.x;
    const int tx = tid & 15, ty = tid >> 4;
    const int lm = tid >> 2, lk4 = (tid & 3) * 4;
    const int kr = tid >> 5;            // 0..7
    const int kn = (tid & 31) * 4;      // 0..124
    float c[4][8] = {};
    const float* Sb = score + ((size_t)bh*LEN + q0)*LEN;
    const float* Kb = kx + (size_t)bh*LEN*HID;

    for (int k0 = 0; k0 < LEN; k0 += 16) {
        float4 sv = *(const float4*)(Sb + (size_t)lm*LEN + k0 + lk4);
        Ss[lk4+0][lm] = sv.x; Ss[lk4+1][lm] = sv.y; Ss[lk4+2][lm] = sv.z; Ss[lk4+3][lm] = sv.w;
        float4 k1 = *(const float4*)(Kb + (size_t)(k0+kr  )*HID + kn);
        float4 k2 = *(const float4*)(Kb + (size_t)(k0+kr+8)*HID + kn);
        *(float4*)&Ks[kr  ][kn] = k1;
        *(float4*)&Ks[kr+8][kn] = k2;
        __syncthreads();
        #pragma unroll
        for (int kk = 0; kk < 16; ++kk) {
            float4 a  = *(const float4*)&Ss[kk][ty*4];
            float4 b0 = *(const float4*)&Ks[kk][tx*8];
            float4 b1 = *(const float4*)&Ks[kk][tx*8+4];
            float ar[4] = {a.x,a.y,a.z,a.w};
            float br[8] = {b0.x,b0.y,b0.z,b0.w,b1.x,b1.y,b1.z,b1.w};
            #pragma unroll
            for (int i = 0; i < 4; ++i)
                #pragma unroll
                for (int j = 0; j < 8; ++j)
                    c[i][j] += ar[i] * br[j];
        }
        __syncthreads();
    }
    #pragma unroll
    for (int i = 0; i < 4; ++i) {
        const int m = q0 + ty*4 + i;
        float* orow = attn + ((size_t)bh*LEN + m)*HID + tx*8;
        #pragma unroll
        for (int j = 0; j < 8; ++j) orow[j] = c[i][j];
    }
}

// ---------------------------------------------------------------------------
// Kernel E: out[m,n] = sum_e attnRe[m,e] * Wp[n,e] + bp[n]
// attn logical [m][e] with e = h*128+hh stored at attn[((h*16+b)*1024+l)*128+hh],
// m = b*1024+l. K-tiles of 16 never straddle an h boundary (16 | 128).
// ---------------------------------------------------------------------------
__global__ __launch_bounds__(256)
void k_proj(const float* __restrict__ A, const float* __restrict__ W,
            const float* __restrict__ bias, float* __restrict__ Y)
{
    const int M0 = blockIdx.y * 64;
    const int N0 = blockIdx.x * 64;
    __shared__ float As[16][68];
    __shared__ float Bs[16][68];
    const int tid = threadIdx.x;
    const int tx = tid & 15, ty = tid >> 4;
    const int lm = tid >> 2;
    const int lk = (tid & 3) * 4;
    float c[4][4] = {};

    for (int k0 = 0; k0 < EMBED; k0 += 16) {
        const int m = M0 + lm;
        const int b = m >> 10, l = m & 1023;
        const int h = k0 >> 7;
        const int hh = (k0 & 127) + lk;
        float4 av = *(const float4*)(A + (((size_t)(h*MB + b))*LEN + l)*HID + hh);
        float4 bv = *(const float4*)(W + (size_t)(N0 + lm) * EMBED + k0 + lk);
        As[lk+0][lm] = av.x; As[lk+1][lm] = av.y; As[lk+2][lm] = av.z; As[lk+3][lm] = av.w;
        Bs[lk+0][lm] = bv.x; Bs[lk+1][lm] = bv.y; Bs[lk+2][lm] = bv.z; Bs[lk+3][lm] = bv.w;
        __syncthreads();
        #pragma unroll
        for (int kk = 0; kk < 16; ++kk) {
            float4 a = *(const float4*)&As[kk][ty*4];
            float4 b = *(const float4*)&Bs[kk][tx*4];
            float ar[4] = {a.x,a.y,a.z,a.w};
            float br[4] = {b.x,b.y,b.z,b.w};
            #pragma unroll
            for (int i = 0; i < 4; ++i)
                #pragma unroll
                for (int j = 0; j < 4; ++j)
                    c[i][j] += ar[i] * br[j];
        }
        __syncthreads();
    }
    #pragma unroll
    for (int i = 0; i < 4; ++i) {
        const int m = M0 + ty*4 + i;
        #pragma unroll
        for (int j = 0; j < 4; ++j) {
            const int n = N0 + tx*4 + j;
            Y[(size_t)m*EMBED + n] = c[i][j] + bias[n];
        }
    }
}

extern "C" void kernel_launch(void* const* d_in, const int* in_sizes, int n_in,
                              void* d_out, int out_size, void* d_ws, size_t ws_size,
                              hipStream_t stream)
{
    const float* k  = (const float*)d_in[0];
    const float* q  = (const float*)d_in[1];
    const float* Wk = (const float*)d_in[2];
    const float* bk = (const float*)d_in[3];
    const float* Wq = (const float*)d_in[4];
    const float* bq = (const float*)d_in[5];
    const float* w  = (const float*)d_in[6];
    const float* Wp = (const float*)d_in[7];
    const float* bp = (const float*)d_in[8];

    float* out   = (float*)d_out;                    // (16,1024,1024) = 16.78M f32
    float* score = out + (size_t)MROWS*EMBED;        // (128,1024,1024) = 134.2M f32

    // Workspace: kx | qx | sk | sq ; attn reuses qx (qx is dead after k_rowdot).
    // Total = 2*67.1 MB + 1 MB = 135.3 MB.
    float* kx   = (float*)d_ws;
    float* qx   = kx + (size_t)BHT*LEN*HID;
    float* sk   = qx + (size_t)BHT*LEN*HID;
    float* sq   = sk + (size_t)BHT*LEN;
    float* attn = qx;  // alias: qx only feeds sq, consumed before k_attnmm

    const dim3 gA(EMBED/64, MROWS/64);
    k_linear_head<<<gA, 256, 0, stream>>>(k, Wk, bk, kx);
    k_linear_head<<<gA, 256, 0, stream>>>(q, Wq, bq, qx);
    k_rowdot<<<(2*BHT*LEN)/4, 256, 0, stream>>>(kx, qx, w, sk, sq);
    k_softmax<<<dim3(LEN, BHT), 256, 0, stream>>>(sk, sq, score);
    k_attnmm<<<dim3(LEN/64, BHT), 256, 0, stream>>>(score, kx, attn);
    k_proj<<<gA, 256, 0, stream>>>(attn, Wp, bp, out);
}